// Round 16
// baseline (219.259 us; speedup 1.0000x reference)
//
#include <hip/hip_runtime.h>
#include <stdint.h>
#include <stddef.h>

typedef unsigned short u16;
typedef float  f32x4  __attribute__((ext_vector_type(4)));
typedef short  s16x8  __attribute__((ext_vector_type(8)));
typedef short  s16x4  __attribute__((ext_vector_type(4)));
typedef __bf16 bf16x8 __attribute__((ext_vector_type(8)));
typedef __bf16 bf16x4 __attribute__((ext_vector_type(4)));
typedef u16    u16x4  __attribute__((ext_vector_type(4)));

#define DEV static __device__ __forceinline__

DEV u16 f2bf(float f){
  uint32_t u = __builtin_bit_cast(uint32_t, f);
  u += 0x7FFFu + ((u >> 16) & 1u);   // round-to-nearest-even
  return (u16)(u >> 16);
}

DEV f32x4 mfma16(s16x8 a, s16x8 b, f32x4 c){
  return __builtin_amdgcn_mfma_f32_16x16x32_bf16(
      __builtin_bit_cast(bf16x8, a), __builtin_bit_cast(bf16x8, b), c, 0, 0, 0);
}

// K=16 bf16 MFMA: B-frag layout == QK^T D-layout -> PV needs no P re-layout.
DEV f32x4 mfma16k(s16x4 a, s16x4 b, f32x4 c){
  return __builtin_amdgcn_mfma_f32_16x16x16bf16_1k(a, b, c, 0, 0, 0);
}

DEV float exp2_fast(float x){ return __builtin_exp2f(x); }

DEV void gl_lds16(const u16* g, u16* l){
  __builtin_amdgcn_global_load_lds(
      (__attribute__((address_space(1))) void*)(g),
      (__attribute__((address_space(3))) void*)(l), 16, 0, 0);
}

// ---------------- fused fp32 -> bf16 convert (x, w_qkv, w_o) ----------------
__global__ __launch_bounds__(256) void cvt_all(const float* __restrict__ x,
                                               const float* __restrict__ wqkv,
                                               const float* __restrict__ wo,
                                               u16* __restrict__ outb){
  const int N1 = 2097152;            // x float4 count
  const int N2 = N1 + 786432;        // + wqkv
  const int NT = N2 + 262144;        // + wo
  const int stride = gridDim.x * blockDim.x;
  for (int i = blockIdx.x * blockDim.x + threadIdx.x; i < NT; i += stride){
    const float* src; int j;
    if (i < N1){ src = x; j = i; }
    else if (i < N2){ src = wqkv; j = i - N1; }
    else { src = wo; j = i - N2; }
    float4 v = *(const float4*)(src + (size_t)j * 4);
    u16x4 o = { f2bf(v.x), f2bf(v.y), f2bf(v.z), f2bf(v.w) };
    *(u16x4*)(outb + (size_t)i * 4) = o;
  }
}

// ------- 128x128 bf16 GEMM core (single-buffer; T2 XOR-swizzled LDS) -------
template<bool SWAPOP>
DEV void gemm_core(const u16* __restrict__ A, const u16* __restrict__ Bw,
                   int K, int bm, int bn, u16* ldsA, u16* ldsB, f32x4 acc[4][4])
{
  const int lane = threadIdx.x & 63;
  const int wave = threadIdx.x >> 6;
  const int wm = (wave >> 1) * 64, wn = (wave & 1) * 64;
  const int lr = lane >> 3;
  const int l8 = (((lane & 7) ^ lr) << 3);   // pre-swizzled source column
  const int fr = lane & 15;
  const int g  = lane >> 4;
  const int f  = fr & 7;

  #pragma unroll
  for (int m = 0; m < 4; m++)
    #pragma unroll
    for (int n = 0; n < 4; n++){ f32x4 z = {0.f,0.f,0.f,0.f}; acc[m][n] = z; }

  const int nkt = K >> 6;
  for (int kt = 0; kt < nkt; ++kt){
    const int kb = kt * 64;
    #pragma unroll
    for (int i = 0; i < 4; i++){
      const int c   = wave * 4 + i;
      const int row = c * 8 + lr;
      gl_lds16(A  + (size_t)(bm + row) * K + kb + l8, ldsA + c * 512);
      gl_lds16(Bw + (size_t)(bn + row) * K + kb + l8, ldsB + c * 512);
    }
    __syncthreads();
    #pragma unroll
    for (int kk = 0; kk < 2; ++kk){
      s16x8 af[4], bfr[4];
      #pragma unroll
      for (int m = 0; m < 4; m++)
        af[m]  = *(const s16x8*)(ldsA + (wm + m*16 + fr)*64 + (((kk*4 + g) ^ f) << 3));
      #pragma unroll
      for (int n = 0; n < 4; n++)
        bfr[n] = *(const s16x8*)(ldsB + (wn + n*16 + fr)*64 + (((kk*4 + g) ^ f) << 3));
      #pragma unroll
      for (int m = 0; m < 4; m++)
        #pragma unroll
        for (int n = 0; n < 4; n++)
          acc[m][n] = SWAPOP ? mfma16(bfr[n], af[m], acc[m][n])
                             : mfma16(af[m], bfr[n], acc[m][n]);
    }
    __syncthreads();
  }
}

// ---------------- QKV projection (T1 XCD-swizzled flat grid) ----------------
// Q pre-scaled by log2(e)/sqrt(dk) so attention works in exp2 domain.
__global__ __launch_bounds__(256, 3) void gemm_qkv(const u16* __restrict__ xb,
                                                   const u16* __restrict__ wb,
                                                   u16* __restrict__ Qd,
                                                   u16* __restrict__ Kd,
                                                   u16* __restrict__ Vtd)
{
  __shared__ __align__(16) u16 ldsA[128*64];
  __shared__ __align__(16) u16 ldsB[128*64];
  f32x4 acc[4][4];
  const int wg  = blockIdx.x;
  const int xcd = wg & 7, rr = wg >> 3;          // rr in [0,192)
  const int bm  = (xcd * 8 + (rr & 7)) * 128;    // 64 bm-tiles
  const int bnt = rr >> 3;                       // 24 bn-tiles
  const int bn  = bnt * 128;
  const int q   = bnt >> 3;                      // 0=Q 1=K 2=V (block-uniform)

  const int lane = threadIdx.x & 63, wave = threadIdx.x >> 6;
  const int wm = (wave >> 1) * 64, wn = (wave & 1) * 64;
  const int fr = lane & 15, r4 = (lane >> 4) * 4;

  if (q < 2){
    gemm_core<true>(xb, wb, 1024, bm, bn, ldsA, ldsB, acc);
    // reg-walk = N (kd); fr = M (s)
    #pragma unroll
    for (int m = 0; m < 4; m++){
      const int s  = bm + wm + m*16 + fr;
      const int b  = s >> 11;
      const int s0 = s & 2047;
      #pragma unroll
      for (int n = 0; n < 4; n++){
        const int ng0 = bn + wn + n*16 + r4;       // 4 consecutive cols
        const int h   = (ng0 >> 6) & 15, kd0 = ng0 & 63;
        const size_t bh = (size_t)(b * 16 + h);
        if (q == 0){
          u16x4 v = { f2bf(acc[m][n][0] * 0.18033688011112042f),
                      f2bf(acc[m][n][1] * 0.18033688011112042f),
                      f2bf(acc[m][n][2] * 0.18033688011112042f),
                      f2bf(acc[m][n][3] * 0.18033688011112042f) };
          *(u16x4*)(Qd + (bh*2048 + s0)*64 + kd0) = v;
        } else {
          u16x4 v = { f2bf(acc[m][n][0]), f2bf(acc[m][n][1]),
                      f2bf(acc[m][n][2]), f2bf(acc[m][n][3]) };
          *(u16x4*)(Kd + (bh*2048 + s0)*64 + kd0) = v;
        }
      }
    }
  } else {
    gemm_core<false>(xb, wb, 1024, bm, bn, ldsA, ldsB, acc);
    // reg-walk = M (s); fr = N (kd) -> transposed Vt store, s contiguous
    #pragma unroll
    for (int m = 0; m < 4; m++){
      const int i0 = bm + wm + m*16 + r4;
      const int b  = i0 >> 11;
      const int s0 = i0 & 2047;
      #pragma unroll
      for (int n = 0; n < 4; n++){
        const int ng = bn + wn + n*16 + fr;
        const int h  = (ng >> 6) & 15, kd = ng & 63;
        const size_t bh = (size_t)(b * 16 + h);
        u16x4 v = { f2bf(acc[m][n][0]), f2bf(acc[m][n][1]),
                    f2bf(acc[m][n][2]), f2bf(acc[m][n][3]) };
        *(u16x4*)(Vtd + (bh*64 + kd)*2048 + s0) = v;
      }
    }
  }
}

// -------- out projection (SWAPOP float4 stores; T1 XCD-swizzled grid) -------
__global__ __launch_bounds__(256, 3) void gemm_outp(const u16* __restrict__ attnb,
                                                    const u16* __restrict__ wob,
                                                    float* __restrict__ C)
{
  __shared__ __align__(16) u16 ldsA[128*64];
  __shared__ __align__(16) u16 ldsB[128*64];
  f32x4 acc[4][4];
  const int wg  = blockIdx.x;
  const int xcd = wg & 7, rr = wg >> 3;          // rr in [0,64)
  const int bm  = (xcd * 8 + (rr & 7)) * 128;    // 64 bm-tiles
  const int bn  = (rr >> 3) * 128;               // 8 bn-tiles
  gemm_core<true>(attnb, wob, 1024, bm, bn, ldsA, ldsB, acc);

  const int lane = threadIdx.x & 63, wave = threadIdx.x >> 6;
  const int wm = (wave >> 1) * 64, wn = (wave & 1) * 64;
  const int fr = lane & 15, r4 = (lane >> 4) * 4;
  #pragma unroll
  for (int m = 0; m < 4; m++){
    const int i0 = bm + wm + m*16 + fr;          // fr = M row
    #pragma unroll
    for (int n = 0; n < 4; n++){
      const int ng0 = bn + wn + n*16 + r4;       // 4 consecutive cols
      *(f32x4*)(C + (size_t)i0 * 1024 + ng0) = acc[m][n];
    }
  }
}

// ---- exp2+pack of one score fragment set (shift-free) ----
DEV void softmax_pack(f32x4 (&sc)[4], s16x4 (&pb)[4], int kb, int q0,
                      int fr, int r4)
{
  if (kb + 63 > q0){                 // diagonal tile: causal mask
    const int q_g = q0 + fr;
    #pragma unroll
    for (int mi = 0; mi < 4; mi++)
      #pragma unroll
      for (int r = 0; r < 4; r++){
        const int s_g = kb + mi*16 + r4 + r;
        sc[mi][r] = (s_g > q_g) ? -1e30f : sc[mi][r];   // exp2 -> 0
      }
  }
  #pragma unroll
  for (int mi = 0; mi < 4; mi++){
    f32x4 e;
    #pragma unroll
    for (int r = 0; r < 4; r++)
      e[r] = exp2_fast(sc[mi][r]);
    pb[mi] = __builtin_bit_cast(s16x4, __builtin_convertvector(e, bf16x4));
  }
}

// ---- solo: one 64-key tile for the HI 16-row q group only ----
DEV void chunk_step1(const u16* Kc, const u16* Vc, int kb, int q0,
                     const s16x8 (&qf)[2], f32x4 (&O)[4], f32x4 &L,
                     s16x4 ones, int fr, int g, int f, int r4)
{
  f32x4 sc[4];
  #pragma unroll
  for (int mi = 0; mi < 4; mi++){ f32x4 z = {0.f,0.f,0.f,0.f}; sc[mi] = z; }
  __builtin_amdgcn_s_setprio(1);
  #pragma unroll
  for (int kk = 0; kk < 2; kk++)
    #pragma unroll
    for (int mi = 0; mi < 4; mi++){
      s16x8 kf = *(const s16x8*)(Kc + (mi*16 + fr)*64 + ((kk*4 + g) ^ f)*8);
      sc[mi] = mfma16(kf, qf[kk], sc[mi]);
    }
  __builtin_amdgcn_s_setprio(0);

  s16x4 pb[4];
  softmax_pack(sc, pb, kb, q0, fr, r4);

  __builtin_amdgcn_s_setprio(1);
  #pragma unroll
  for (int mi = 0; mi < 4; mi++){
    L = mfma16k(ones, pb[mi], L);
    #pragma unroll
    for (int n = 0; n < 4; n++){
      s16x4 vf = *(const s16x4*)(Vc + (n*16 + fr)*64 + ((2*mi + (g >> 1)) ^ f)*8 + (g & 1)*4);
      O[n] = mfma16k(vf, pb[mi], O[n]);
    }
  }
  __builtin_amdgcn_s_setprio(0);
}

// ---- fused: one 64-key tile for BOTH chunks, kf AND vf loaded once ----
// sch/scl die into pbh/pbl before PV -> peak live ~108 VGPR, fits the 128
// budget at 4 waves/EU (amdgpu_waves_per_eu(4,4) pins the allocator there).
DEV void chunk_dual(const u16* Kc, const u16* Vc, int kb, int qh0, int ql0,
                    const s16x8 (&qfh)[2], const s16x8 (&qfl)[2],
                    f32x4 (&Oh)[4], f32x4 (&Ol)[4], f32x4 &Lh, f32x4 &Ll,
                    s16x4 ones, int fr, int g, int f, int r4)
{
  f32x4 sch[4], scl[4];
  #pragma unroll
  for (int mi = 0; mi < 4; mi++){
    f32x4 z = {0.f,0.f,0.f,0.f}; sch[mi] = z; scl[mi] = z;
  }
  __builtin_amdgcn_s_setprio(1);
  #pragma unroll
  for (int kk = 0; kk < 2; kk++)
    #pragma unroll
    for (int mi = 0; mi < 4; mi++){
      s16x8 kf = *(const s16x8*)(Kc + (mi*16 + fr)*64 + ((kk*4 + g) ^ f)*8);
      sch[mi] = mfma16(kf, qfh[kk], sch[mi]);
      scl[mi] = mfma16(kf, qfl[kk], scl[mi]);
    }
  __builtin_amdgcn_s_setprio(0);

  s16x4 pbh[4], pbl[4];
  softmax_pack(sch, pbh, kb, qh0, fr, r4);   // hi never masked in dual steps
  softmax_pack(scl, pbl, kb, ql0, fr, r4);

  __builtin_amdgcn_s_setprio(1);
  #pragma unroll
  for (int mi = 0; mi < 4; mi++){
    Lh = mfma16k(ones, pbh[mi], Lh);
    Ll = mfma16k(ones, pbl[mi], Ll);
    #pragma unroll
    for (int n = 0; n < 4; n++){
      s16x4 vf = *(const s16x4*)(Vc + (n*16 + fr)*64 + ((2*mi + (g >> 1)) ^ f)*8 + (g & 1)*4);
      Oh[n] = mfma16k(vf, pbh[mi], Oh[n]);
      Ol[n] = mfma16k(vf, pbl[mi], Ol[n]);
    }
  }
  __builtin_amdgcn_s_setprio(0);
}

// ------- causal flash attention (v9: fused dual steps, allocator pinned) ----
__attribute__((amdgpu_waves_per_eu(4, 4)))
__global__ __launch_bounds__(256) void attn_fwd(const u16* __restrict__ Qd,
                                                const u16* __restrict__ Kd,
                                                const u16* __restrict__ Vtd,
                                                u16* __restrict__ attnb)
{
  __shared__ __align__(16) u16 Kl[2][64*64];
  __shared__ __align__(16) u16 Vl[2][64*64];

  const int t = threadIdx.x;
  const int lane = t & 63, w = t >> 6;
  const int wg = blockIdx.x;
  const int bh = 8 * (wg & 7) + (wg >> 7);   // same bh -> same XCD
  const int ph = (wg >> 3) & 15;
  const int p  = ph >> 1, half = ph & 1;
  const int qh = 8 + p, ql = 7 - p;          // complementary pair
  const u16* Qp = Qd  + (size_t)bh * 2048 * 64;
  const u16* Kp = Kd  + (size_t)bh * 2048 * 64;
  const u16* Vp = Vtd + (size_t)bh * 64 * 2048;

  const int fr = lane & 15, g = lane >> 4;
  const int f  = fr & 7;
  const int k8 = g * 8, r4 = g * 4;
  const int rgs = half * 4 + w;              // rg slot 0..7 within each chunk
  const int qh0 = qh * 128 + rgs * 16;
  const int ql0 = ql * 128 + rgs * 16;
  const int nkt = 2 * qh + 2;

  const s16x4 ones = { 0x3F80, 0x3F80, 0x3F80, 0x3F80 };   // bf16 1.0

  s16x8 qfh[2], qfl[2];
  #pragma unroll
  for (int kk = 0; kk < 2; kk++){
    qfh[kk] = *(const s16x8*)(Qp + (size_t)(qh0 + fr) * 64 + kk*32 + k8);
    qfl[kk] = *(const s16x8*)(Qp + (size_t)(ql0 + fr) * 64 + kk*32 + k8);
  }

  f32x4 Ohi[4], Olo[4], Lhi, Llo;
  #pragma unroll
  for (int n = 0; n < 4; n++){
    f32x4 z = {0.f,0.f,0.f,0.f}; Ohi[n] = z; Olo[n] = z;
  }
  { f32x4 z = {0.f,0.f,0.f,0.f}; Lhi = z; Llo = z; }

  // staging pointers (swizzled source, linear LDS dest), incremented per tile
  const int Lr  = t >> 3;
  const int cs8 = ((t & 7) ^ (Lr & 7)) * 8;
  const u16* kS = Kp + Lr * 64 + cs8;
  const u16* vS = Vp + (size_t)Lr * 2048 + cs8;

  // stage tile 0 into buffer 0
  gl_lds16(kS,         (u16*)Kl + t*8);
  gl_lds16(kS + 2048,  (u16*)Kl + t*8 + 2048);
  gl_lds16(vS,         (u16*)Vl + t*8);
  gl_lds16(vS + 65536, (u16*)Vl + t*8 + 2048);
  kS += 4096; vS += 64;

  for (int kt = 0; kt < nkt; ++kt){
    __syncthreads();
    const int cur = kt & 1;
    if (kt + 1 < nkt){
      u16* kD = (u16*)Kl + (cur ^ 1) * 4096 + t*8;
      u16* vD = (u16*)Vl + (cur ^ 1) * 4096 + t*8;
      gl_lds16(kS,         kD);
      gl_lds16(kS + 2048,  kD + 2048);
      gl_lds16(vS,         vD);
      gl_lds16(vS + 65536, vD + 2048);
    }
    kS += 4096; vS += 64;

    const int kb = kt * 64;
    const u16* Kc = Kl[cur];
    const u16* Vc = Vl[cur];

    if (kb <= ql0 + 15)            // lo active => hi active (ql0 < qh0)
      chunk_dual(Kc, Vc, kb, qh0, ql0, qfh, qfl,
                 Ohi, Olo, Lhi, Llo, ones, fr, g, f, r4);
    else if (kb <= qh0 + 15)
      chunk_step1(Kc, Vc, kb, qh0, qfh, Ohi, Lhi, ones, fr, g, f, r4);
  }

  // ---- epilogue: L[0] is the fully-reduced softmax denominator ----
  const int b = bh >> 4, h = bh & 15;
  const float invh = 1.0f / Lhi[0];
  const float invl = 1.0f / Llo[0];
  const int sh = qh0 + fr;
  const int sl = ql0 + fr;
  #pragma unroll
  for (int n = 0; n < 4; n++){
    u16x4 vh = { f2bf(Ohi[n][0]*invh), f2bf(Ohi[n][1]*invh),
                 f2bf(Ohi[n][2]*invh), f2bf(Ohi[n][3]*invh) };
    *(u16x4*)(attnb + (((size_t)b*2048 + sh)*16 + h)*64 + n*16 + r4) = vh;
    u16x4 vl = { f2bf(Olo[n][0]*invl), f2bf(Olo[n][1]*invl),
                 f2bf(Olo[n][2]*invl), f2bf(Olo[n][3]*invl) };
    *(u16x4*)(attnb + (((size_t)b*2048 + sl)*16 + h)*64 + n*16 + r4) = vl;
  }
}

// ---------------- host launch ----------------
extern "C" void kernel_launch(void* const* d_in, const int* in_sizes, int n_in,
                              void* d_out, int out_size, void* d_ws, size_t ws_size,
                              hipStream_t stream)
{
  const float* x    = (const float*)d_in[0];   // (4,2048,1024)
  const float* wqkv = (const float*)d_in[1];   // (3,16,64,1024)
  const float* wo   = (const float*)d_in[2];   // (1024,1024)
  float* out = (float*)d_out;

  char* ws = (char*)d_ws;
  u16* xb    = (u16*)(ws);                     // xb/wqb/wob contiguous (cvt_all)
  u16* wqb   = (u16*)(ws + 16777216);
  u16* wob   = (u16*)(ws + 23068672);
  u16* Qd    = (u16*)(ws + 25165824);
  u16* Kd    = (u16*)(ws + 41943040);
  u16* Vtd   = (u16*)(ws + 58720256);
  u16* attnb = xb;                             // x dead after gemm_qkv

  cvt_all<<<3072, 256, 0, stream>>>(x, wqkv, wo, xb);
  gemm_qkv<<<dim3(1536), 256, 0, stream>>>(xb, wqb, Qd, Kd, Vtd);
  attn_fwd<<<dim3(1024), 256, 0, stream>>>(Qd, Kd, Vtd, attnb);
  gemm_outp<<<dim3(512), 256, 0, stream>>>(attnb, wob, out);
}

// Round 17
// 187.095 us; speedup vs baseline: 1.1719x; 1.1719x over previous
//
#include <hip/hip_runtime.h>
#include <stdint.h>
#include <stddef.h>

typedef unsigned short u16;
typedef float  f32x4  __attribute__((ext_vector_type(4)));
typedef short  s16x8  __attribute__((ext_vector_type(8)));
typedef short  s16x4  __attribute__((ext_vector_type(4)));
typedef __bf16 bf16x8 __attribute__((ext_vector_type(8)));
typedef __bf16 bf16x4 __attribute__((ext_vector_type(4)));
typedef u16    u16x4  __attribute__((ext_vector_type(4)));
typedef u16    u16x8  __attribute__((ext_vector_type(8)));

#define DEV static __device__ __forceinline__

DEV u16 f2bf(float f){
  uint32_t u = __builtin_bit_cast(uint32_t, f);
  u += 0x7FFFu + ((u >> 16) & 1u);   // round-to-nearest-even
  return (u16)(u >> 16);
}

DEV f32x4 mfma16(s16x8 a, s16x8 b, f32x4 c){
  return __builtin_amdgcn_mfma_f32_16x16x32_bf16(
      __builtin_bit_cast(bf16x8, a), __builtin_bit_cast(bf16x8, b), c, 0, 0, 0);
}

// K=16 bf16 MFMA: B-frag layout == QK^T D-layout -> PV needs no P re-layout.
DEV f32x4 mfma16k(s16x4 a, s16x4 b, f32x4 c){
  return __builtin_amdgcn_mfma_f32_16x16x16bf16_1k(a, b, c, 0, 0, 0);
}

DEV float exp2_fast(float x){ return __builtin_exp2f(x); }

DEV void gl_lds16(const u16* g, u16* l){
  __builtin_amdgcn_global_load_lds(
      (__attribute__((address_space(1))) void*)(g),
      (__attribute__((address_space(3))) void*)(l), 16, 0, 0);
}

// ---------------- fp32 -> bf16 convert, WEIGHTS ONLY (w_qkv, w_o) ----------
// x's conversion is fused into gemm_qkv's A-staging (saves 48 MB of traffic).
__global__ __launch_bounds__(256) void cvt_w(const float* __restrict__ wqkv,
                                             const float* __restrict__ wo,
                                             u16* __restrict__ outb){
  const int N1 = 786432;             // wqkv float4 count
  const int NT = N1 + 262144;        // + wo
  const int stride = gridDim.x * blockDim.x;
  for (int i = blockIdx.x * blockDim.x + threadIdx.x; i < NT; i += stride){
    const float* src; int j;
    if (i < N1){ src = wqkv; j = i; }
    else { src = wo; j = i - N1; }
    float4 v = *(const float4*)(src + (size_t)j * 4);
    u16x4 o = { f2bf(v.x), f2bf(v.y), f2bf(v.z), f2bf(v.w) };
    *(u16x4*)(outb + (size_t)i * 4) = o;
  }
}

// ------- 128x128 bf16 GEMM core (single-buffer; T2 XOR-swizzled LDS) -------
// AF32: A is fp32 in global; reg-stage (load 32B fp32 -> cvt_pk -> one
// ds_write_b128 to the SAME linear dest gl_lds would use; read side
// unchanged). End-of-iter barrier protects the overwrite, as it did for
// gl_lds. B always stages via global_load_lds.
template<bool SWAPOP, bool AF32>
DEV void gemm_core(const void* __restrict__ Av, const u16* __restrict__ Bw,
                   int K, int bm, int bn, u16* ldsA, u16* ldsB, f32x4 acc[4][4])
{
  const u16*   A16 = (const u16*)Av;
  const float* A32 = (const float*)Av;
  const int lane = threadIdx.x & 63;
  const int wave = threadIdx.x >> 6;
  const int wm = (wave >> 1) * 64, wn = (wave & 1) * 64;
  const int lr = lane >> 3;
  const int l8 = (((lane & 7) ^ lr) << 3);   // pre-swizzled source column
  const int fr = lane & 15;
  const int g  = lane >> 4;
  const int f  = fr & 7;

  #pragma unroll
  for (int m = 0; m < 4; m++)
    #pragma unroll
    for (int n = 0; n < 4; n++){ f32x4 z = {0.f,0.f,0.f,0.f}; acc[m][n] = z; }

  const int nkt = K >> 6;
  for (int kt = 0; kt < nkt; ++kt){
    const int kb = kt * 64;
    #pragma unroll
    for (int i = 0; i < 4; i++){
      const int c   = wave * 4 + i;
      const int row = c * 8 + lr;
      if constexpr (AF32){
        const float* s = A32 + (size_t)(bm + row) * K + kb + l8;
        f32x4 v0 = *(const f32x4*)s;
        f32x4 v1 = *(const f32x4*)(s + 4);
        u16x4 lo = __builtin_bit_cast(u16x4, __builtin_convertvector(v0, bf16x4));
        u16x4 hi = __builtin_bit_cast(u16x4, __builtin_convertvector(v1, bf16x4));
        u16x8 o = { lo[0], lo[1], lo[2], lo[3], hi[0], hi[1], hi[2], hi[3] };
        *(u16x8*)(ldsA + c * 512 + lane * 8) = o;   // linear dest (== gl_lds)
      } else {
        gl_lds16(A16 + (size_t)(bm + row) * K + kb + l8, ldsA + c * 512);
      }
      gl_lds16(Bw + (size_t)(bn + row) * K + kb + l8, ldsB + c * 512);
    }
    __syncthreads();
    #pragma unroll
    for (int kk = 0; kk < 2; ++kk){
      s16x8 af[4], bfr[4];
      #pragma unroll
      for (int m = 0; m < 4; m++)
        af[m]  = *(const s16x8*)(ldsA + (wm + m*16 + fr)*64 + (((kk*4 + g) ^ f) << 3));
      #pragma unroll
      for (int n = 0; n < 4; n++)
        bfr[n] = *(const s16x8*)(ldsB + (wn + n*16 + fr)*64 + (((kk*4 + g) ^ f) << 3));
      #pragma unroll
      for (int m = 0; m < 4; m++)
        #pragma unroll
        for (int n = 0; n < 4; n++)
          acc[m][n] = SWAPOP ? mfma16(bfr[n], af[m], acc[m][n])
                             : mfma16(af[m], bfr[n], acc[m][n]);
    }
    __syncthreads();
  }
}

// ---------- QKV projection (fused x-conversion; T1 XCD-swizzled grid) -------
// Q pre-scaled by log2(e)/sqrt(dk) so attention works in exp2 domain.
__global__ __launch_bounds__(256, 3) void gemm_qkv(const float* __restrict__ x,
                                                   const u16* __restrict__ wb,
                                                   u16* __restrict__ Qd,
                                                   u16* __restrict__ Kd,
                                                   u16* __restrict__ Vtd)
{
  __shared__ __align__(16) u16 ldsA[128*64];
  __shared__ __align__(16) u16 ldsB[128*64];
  f32x4 acc[4][4];
  const int wg  = blockIdx.x;
  const int xcd = wg & 7, rr = wg >> 3;          // rr in [0,192)
  const int bm  = (xcd * 8 + (rr & 7)) * 128;    // 64 bm-tiles
  const int bnt = rr >> 3;                       // 24 bn-tiles
  const int bn  = bnt * 128;
  const int q   = bnt >> 3;                      // 0=Q 1=K 2=V (block-uniform)

  const int lane = threadIdx.x & 63, wave = threadIdx.x >> 6;
  const int wm = (wave >> 1) * 64, wn = (wave & 1) * 64;
  const int fr = lane & 15, r4 = (lane >> 4) * 4;

  if (q < 2){
    gemm_core<true, true>(x, wb, 1024, bm, bn, ldsA, ldsB, acc);
    // reg-walk = N (kd); fr = M (s)
    #pragma unroll
    for (int m = 0; m < 4; m++){
      const int s  = bm + wm + m*16 + fr;
      const int b  = s >> 11;
      const int s0 = s & 2047;
      #pragma unroll
      for (int n = 0; n < 4; n++){
        const int ng0 = bn + wn + n*16 + r4;       // 4 consecutive cols
        const int h   = (ng0 >> 6) & 15, kd0 = ng0 & 63;
        const size_t bh = (size_t)(b * 16 + h);
        if (q == 0){
          u16x4 v = { f2bf(acc[m][n][0] * 0.18033688011112042f),
                      f2bf(acc[m][n][1] * 0.18033688011112042f),
                      f2bf(acc[m][n][2] * 0.18033688011112042f),
                      f2bf(acc[m][n][3] * 0.18033688011112042f) };
          *(u16x4*)(Qd + (bh*2048 + s0)*64 + kd0) = v;
        } else {
          u16x4 v = { f2bf(acc[m][n][0]), f2bf(acc[m][n][1]),
                      f2bf(acc[m][n][2]), f2bf(acc[m][n][3]) };
          *(u16x4*)(Kd + (bh*2048 + s0)*64 + kd0) = v;
        }
      }
    }
  } else {
    gemm_core<false, true>(x, wb, 1024, bm, bn, ldsA, ldsB, acc);
    // reg-walk = M (s); fr = N (kd) -> transposed Vt store, s contiguous
    #pragma unroll
    for (int m = 0; m < 4; m++){
      const int i0 = bm + wm + m*16 + r4;
      const int b  = i0 >> 11;
      const int s0 = i0 & 2047;
      #pragma unroll
      for (int n = 0; n < 4; n++){
        const int ng = bn + wn + n*16 + fr;
        const int h  = (ng >> 6) & 15, kd = ng & 63;
        const size_t bh = (size_t)(b * 16 + h);
        u16x4 v = { f2bf(acc[m][n][0]), f2bf(acc[m][n][1]),
                    f2bf(acc[m][n][2]), f2bf(acc[m][n][3]) };
        *(u16x4*)(Vtd + (bh*64 + kd)*2048 + s0) = v;
      }
    }
  }
}

// -------- out projection (SWAPOP float4 stores; T1 XCD-swizzled grid) -------
__global__ __launch_bounds__(256, 3) void gemm_outp(const u16* __restrict__ attnb,
                                                    const u16* __restrict__ wob,
                                                    float* __restrict__ C)
{
  __shared__ __align__(16) u16 ldsA[128*64];
  __shared__ __align__(16) u16 ldsB[128*64];
  f32x4 acc[4][4];
  const int wg  = blockIdx.x;
  const int xcd = wg & 7, rr = wg >> 3;          // rr in [0,64)
  const int bm  = (xcd * 8 + (rr & 7)) * 128;    // 64 bm-tiles
  const int bn  = (rr >> 3) * 128;               // 8 bn-tiles
  gemm_core<true, false>(attnb, wob, 1024, bm, bn, ldsA, ldsB, acc);

  const int lane = threadIdx.x & 63, wave = threadIdx.x >> 6;
  const int wm = (wave >> 1) * 64, wn = (wave & 1) * 64;
  const int fr = lane & 15, r4 = (lane >> 4) * 4;
  #pragma unroll
  for (int m = 0; m < 4; m++){
    const int i0 = bm + wm + m*16 + fr;          // fr = M row
    #pragma unroll
    for (int n = 0; n < 4; n++){
      const int ng0 = bn + wn + n*16 + r4;       // 4 consecutive cols
      *(f32x4*)(C + (size_t)i0 * 1024 + ng0) = acc[m][n];
    }
  }
}

// ---- exp2+pack of one score fragment set (shift-free) ----
DEV void softmax_pack(f32x4 (&sc)[4], s16x4 (&pb)[4], int kb, int q0,
                      int fr, int r4)
{
  if (kb + 63 > q0){                 // diagonal tile: causal mask
    const int q_g = q0 + fr;
    #pragma unroll
    for (int mi = 0; mi < 4; mi++)
      #pragma unroll
      for (int r = 0; r < 4; r++){
        const int s_g = kb + mi*16 + r4 + r;
        sc[mi][r] = (s_g > q_g) ? -1e30f : sc[mi][r];   // exp2 -> 0
      }
  }
  #pragma unroll
  for (int mi = 0; mi < 4; mi++){
    f32x4 e;
    #pragma unroll
    for (int r = 0; r < 4; r++)
      e[r] = exp2_fast(sc[mi][r]);
    pb[mi] = __builtin_bit_cast(s16x4, __builtin_convertvector(e, bf16x4));
  }
}

// ---- one 64-key tile for ONE 16-row q group ----
DEV void chunk_step1(const u16* Kc, const u16* Vc, int kb, int q0,
                     const s16x8 (&qf)[2], f32x4 (&O)[4], f32x4 &L,
                     s16x4 ones, int fr, int g, int f, int r4)
{
  f32x4 sc[4];
  #pragma unroll
  for (int mi = 0; mi < 4; mi++){ f32x4 z = {0.f,0.f,0.f,0.f}; sc[mi] = z; }
  __builtin_amdgcn_s_setprio(1);
  #pragma unroll
  for (int kk = 0; kk < 2; kk++)
    #pragma unroll
    for (int mi = 0; mi < 4; mi++){
      s16x8 kf = *(const s16x8*)(Kc + (mi*16 + fr)*64 + ((kk*4 + g) ^ f)*8);
      sc[mi] = mfma16(kf, qf[kk], sc[mi]);
    }
  __builtin_amdgcn_s_setprio(0);

  s16x4 pb[4];
  softmax_pack(sc, pb, kb, q0, fr, r4);

  __builtin_amdgcn_s_setprio(1);
  #pragma unroll
  for (int mi = 0; mi < 4; mi++){
    L = mfma16k(ones, pb[mi], L);
    #pragma unroll
    for (int n = 0; n < 4; n++){
      s16x4 vf = *(const s16x4*)(Vc + (n*16 + fr)*64 + ((2*mi + (g >> 1)) ^ f)*8 + (g & 1)*4);
      O[n] = mfma16k(vf, pb[mi], O[n]);
    }
  }
  __builtin_amdgcn_s_setprio(0);
}

// ------- causal flash attention (v7: half-pair blocks, shift-free SM) -------
__global__ __launch_bounds__(256, 4) void attn_fwd(const u16* __restrict__ Qd,
                                                   const u16* __restrict__ Kd,
                                                   const u16* __restrict__ Vtd,
                                                   u16* __restrict__ attnb)
{
  __shared__ __align__(16) u16 Kl[2][64*64];
  __shared__ __align__(16) u16 Vl[2][64*64];

  const int t = threadIdx.x;
  const int lane = t & 63, w = t >> 6;
  const int wg = blockIdx.x;
  const int bh = 8 * (wg & 7) + (wg >> 7);   // same bh -> same XCD
  const int ph = (wg >> 3) & 15;
  const int p  = ph >> 1, half = ph & 1;
  const int qh = 8 + p, ql = 7 - p;          // complementary pair
  const u16* Qp = Qd  + (size_t)bh * 2048 * 64;
  const u16* Kp = Kd  + (size_t)bh * 2048 * 64;
  const u16* Vp = Vtd + (size_t)bh * 64 * 2048;

  const int fr = lane & 15, g = lane >> 4;
  const int f  = fr & 7;
  const int k8 = g * 8, r4 = g * 4;
  const int rgs = half * 4 + w;              // rg slot 0..7 within each chunk
  const int qh0 = qh * 128 + rgs * 16;
  const int ql0 = ql * 128 + rgs * 16;
  const int nkt = 2 * qh + 2;

  const s16x4 ones = { 0x3F80, 0x3F80, 0x3F80, 0x3F80 };   // bf16 1.0

  s16x8 qfh[2], qfl[2];
  #pragma unroll
  for (int kk = 0; kk < 2; kk++){
    qfh[kk] = *(const s16x8*)(Qp + (size_t)(qh0 + fr) * 64 + kk*32 + k8);
    qfl[kk] = *(const s16x8*)(Qp + (size_t)(ql0 + fr) * 64 + kk*32 + k8);
  }

  f32x4 Ohi[4], Olo[4], Lhi, Llo;
  #pragma unroll
  for (int n = 0; n < 4; n++){
    f32x4 z = {0.f,0.f,0.f,0.f}; Ohi[n] = z; Olo[n] = z;
  }
  { f32x4 z = {0.f,0.f,0.f,0.f}; Lhi = z; Llo = z; }

  // staging pointers (swizzled source, linear LDS dest), incremented per tile
  const int Lr  = t >> 3;
  const int cs8 = ((t & 7) ^ (Lr & 7)) * 8;
  const u16* kS = Kp + Lr * 64 + cs8;
  const u16* vS = Vp + (size_t)Lr * 2048 + cs8;

  // stage tile 0 into buffer 0
  gl_lds16(kS,         (u16*)Kl + t*8);
  gl_lds16(kS + 2048,  (u16*)Kl + t*8 + 2048);
  gl_lds16(vS,         (u16*)Vl + t*8);
  gl_lds16(vS + 65536, (u16*)Vl + t*8 + 2048);
  kS += 4096; vS += 64;

  for (int kt = 0; kt < nkt; ++kt){
    __syncthreads();
    const int cur = kt & 1;
    if (kt + 1 < nkt){
      u16* kD = (u16*)Kl + (cur ^ 1) * 4096 + t*8;
      u16* vD = (u16*)Vl + (cur ^ 1) * 4096 + t*8;
      gl_lds16(kS,         kD);
      gl_lds16(kS + 2048,  kD + 2048);
      gl_lds16(vS,         vD);
      gl_lds16(vS + 65536, vD + 2048);
    }
    kS += 4096; vS += 64;

    const int kb = kt * 64;
    const u16* Kc = Kl[cur];
    const u16* Vc = Vl[cur];

    if (kb <= qh0 + 15)
      chunk_step1(Kc, Vc, kb, qh0, qfh, Ohi, Lhi, ones, fr, g, f, r4);
    if (kb <= ql0 + 15)
      chunk_step1(Kc, Vc, kb, ql0, qfl, Olo, Llo, ones, fr, g, f, r4);
  }

  // ---- epilogue: L[0] is the fully-reduced softmax denominator ----
  const int b = bh >> 4, h = bh & 15;
  const float invh = 1.0f / Lhi[0];
  const float invl = 1.0f / Llo[0];
  const int sh = qh0 + fr;
  const int sl = ql0 + fr;
  #pragma unroll
  for (int n = 0; n < 4; n++){
    u16x4 vh = { f2bf(Ohi[n][0]*invh), f2bf(Ohi[n][1]*invh),
                 f2bf(Ohi[n][2]*invh), f2bf(Ohi[n][3]*invh) };
    *(u16x4*)(attnb + (((size_t)b*2048 + sh)*16 + h)*64 + n*16 + r4) = vh;
    u16x4 vl = { f2bf(Olo[n][0]*invl), f2bf(Olo[n][1]*invl),
                 f2bf(Olo[n][2]*invl), f2bf(Olo[n][3]*invl) };
    *(u16x4*)(attnb + (((size_t)b*2048 + sl)*16 + h)*64 + n*16 + r4) = vl;
  }
}

// ---------------- host launch ----------------
extern "C" void kernel_launch(void* const* d_in, const int* in_sizes, int n_in,
                              void* d_out, int out_size, void* d_ws, size_t ws_size,
                              hipStream_t stream)
{
  const float* x    = (const float*)d_in[0];   // (4,2048,1024)
  const float* wqkv = (const float*)d_in[1];   // (3,16,64,1024)
  const float* wo   = (const float*)d_in[2];   // (1024,1024)
  float* out = (float*)d_out;

  char* ws = (char*)d_ws;
  u16* attnb = (u16*)(ws);                     // former xb region (free)
  u16* wqb   = (u16*)(ws + 16777216);          // wqb/wob contiguous (cvt_w)
  u16* wob   = (u16*)(ws + 23068672);
  u16* Qd    = (u16*)(ws + 25165824);
  u16* Kd    = (u16*)(ws + 41943040);
  u16* Vtd   = (u16*)(ws + 58720256);

  cvt_w<<<1024, 256, 0, stream>>>(wqkv, wo, wqb);
  gemm_qkv<<<dim3(1536), 256, 0, stream>>>(x, wqb, Qd, Kd, Vtd);
  attn_fwd<<<dim3(1024), 256, 0, stream>>>(Qd, Kd, Vtd, attnb);
  gemm_outp<<<dim3(512), 256, 0, stream>>>(attnb, wob, out);
}

// Round 18
// 180.952 us; speedup vs baseline: 1.2117x; 1.0340x over previous
//
#include <hip/hip_runtime.h>
#include <stdint.h>
#include <stddef.h>

typedef unsigned short u16;
typedef float  f32x4  __attribute__((ext_vector_type(4)));
typedef short  s16x8  __attribute__((ext_vector_type(8)));
typedef short  s16x4  __attribute__((ext_vector_type(4)));
typedef __bf16 bf16x8 __attribute__((ext_vector_type(8)));
typedef __bf16 bf16x4 __attribute__((ext_vector_type(4)));
typedef u16    u16x4  __attribute__((ext_vector_type(4)));

#define DEV static __device__ __forceinline__

DEV u16 f2bf(float f){
  uint32_t u = __builtin_bit_cast(uint32_t, f);
  u += 0x7FFFu + ((u >> 16) & 1u);   // round-to-nearest-even
  return (u16)(u >> 16);
}

DEV f32x4 mfma16(s16x8 a, s16x8 b, f32x4 c){
  return __builtin_amdgcn_mfma_f32_16x16x32_bf16(
      __builtin_bit_cast(bf16x8, a), __builtin_bit_cast(bf16x8, b), c, 0, 0, 0);
}

// K=16 bf16 MFMA: B-frag layout == QK^T D-layout -> PV needs no P re-layout.
DEV f32x4 mfma16k(s16x4 a, s16x4 b, f32x4 c){
  return __builtin_amdgcn_mfma_f32_16x16x16bf16_1k(a, b, c, 0, 0, 0);
}

DEV float exp2_fast(float x){ return __builtin_exp2f(x); }

DEV void gl_lds16(const u16* g, u16* l){
  __builtin_amdgcn_global_load_lds(
      (__attribute__((address_space(1))) void*)(g),
      (__attribute__((address_space(3))) void*)(l), 16, 0, 0);
}

// ---------------- fused fp32 -> bf16 convert (x, w_qkv, w_o) ----------------
__global__ __launch_bounds__(256) void cvt_all(const float* __restrict__ x,
                                               const float* __restrict__ wqkv,
                                               const float* __restrict__ wo,
                                               u16* __restrict__ outb){
  const int N1 = 2097152;            // x float4 count
  const int N2 = N1 + 786432;        // + wqkv
  const int NT = N2 + 262144;        // + wo
  const int stride = gridDim.x * blockDim.x;
  for (int i = blockIdx.x * blockDim.x + threadIdx.x; i < NT; i += stride){
    const float* src; int j;
    if (i < N1){ src = x; j = i; }
    else if (i < N2){ src = wqkv; j = i - N1; }
    else { src = wo; j = i - N2; }
    float4 v = *(const float4*)(src + (size_t)j * 4);
    u16x4 o = { f2bf(v.x), f2bf(v.y), f2bf(v.z), f2bf(v.w) };
    *(u16x4*)(outb + (size_t)i * 4) = o;
  }
}

// ------- 128x128 bf16 GEMM core (single-buffer; T2 XOR-swizzled LDS) -------
template<bool SWAPOP>
DEV void gemm_core(const u16* __restrict__ A, const u16* __restrict__ Bw,
                   int K, int bm, int bn, u16* ldsA, u16* ldsB, f32x4 acc[4][4])
{
  const int lane = threadIdx.x & 63;
  const int wave = threadIdx.x >> 6;
  const int wm = (wave >> 1) * 64, wn = (wave & 1) * 64;
  const int lr = lane >> 3;
  const int l8 = (((lane & 7) ^ lr) << 3);   // pre-swizzled source column
  const int fr = lane & 15;
  const int g  = lane >> 4;
  const int f  = fr & 7;

  #pragma unroll
  for (int m = 0; m < 4; m++)
    #pragma unroll
    for (int n = 0; n < 4; n++){ f32x4 z = {0.f,0.f,0.f,0.f}; acc[m][n] = z; }

  const int nkt = K >> 6;
  for (int kt = 0; kt < nkt; ++kt){
    const int kb = kt * 64;
    #pragma unroll
    for (int i = 0; i < 4; i++){
      const int c   = wave * 4 + i;
      const int row = c * 8 + lr;
      gl_lds16(A  + (size_t)(bm + row) * K + kb + l8, ldsA + c * 512);
      gl_lds16(Bw + (size_t)(bn + row) * K + kb + l8, ldsB + c * 512);
    }
    __syncthreads();
    #pragma unroll
    for (int kk = 0; kk < 2; ++kk){
      s16x8 af[4], bfr[4];
      #pragma unroll
      for (int m = 0; m < 4; m++)
        af[m]  = *(const s16x8*)(ldsA + (wm + m*16 + fr)*64 + (((kk*4 + g) ^ f) << 3));
      #pragma unroll
      for (int n = 0; n < 4; n++)
        bfr[n] = *(const s16x8*)(ldsB + (wn + n*16 + fr)*64 + (((kk*4 + g) ^ f) << 3));
      #pragma unroll
      for (int m = 0; m < 4; m++)
        #pragma unroll
        for (int n = 0; n < 4; n++)
          acc[m][n] = SWAPOP ? mfma16(bfr[n], af[m], acc[m][n])
                             : mfma16(af[m], bfr[n], acc[m][n]);
    }
    __syncthreads();
  }
}

// ---------------- QKV projection (T1 XCD-swizzled flat grid) ----------------
// Q pre-scaled by log2(e)/sqrt(dk) so attention works in exp2 domain.
__global__ __launch_bounds__(256, 3) void gemm_qkv(const u16* __restrict__ xb,
                                                   const u16* __restrict__ wb,
                                                   u16* __restrict__ Qd,
                                                   u16* __restrict__ Kd,
                                                   u16* __restrict__ Vtd)
{
  __shared__ __align__(16) u16 ldsA[128*64];
  __shared__ __align__(16) u16 ldsB[128*64];
  f32x4 acc[4][4];
  const int wg  = blockIdx.x;
  const int xcd = wg & 7, rr = wg >> 3;          // rr in [0,192)
  const int bm  = (xcd * 8 + (rr & 7)) * 128;    // 64 bm-tiles
  const int bnt = rr >> 3;                       // 24 bn-tiles
  const int bn  = bnt * 128;
  const int q   = bnt >> 3;                      // 0=Q 1=K 2=V (block-uniform)

  const int lane = threadIdx.x & 63, wave = threadIdx.x >> 6;
  const int wm = (wave >> 1) * 64, wn = (wave & 1) * 64;
  const int fr = lane & 15, r4 = (lane >> 4) * 4;

  if (q < 2){
    gemm_core<true>(xb, wb, 1024, bm, bn, ldsA, ldsB, acc);
    // reg-walk = N (kd); fr = M (s)
    #pragma unroll
    for (int m = 0; m < 4; m++){
      const int s  = bm + wm + m*16 + fr;
      const int b  = s >> 11;
      const int s0 = s & 2047;
      #pragma unroll
      for (int n = 0; n < 4; n++){
        const int ng0 = bn + wn + n*16 + r4;       // 4 consecutive cols
        const int h   = (ng0 >> 6) & 15, kd0 = ng0 & 63;
        const size_t bh = (size_t)(b * 16 + h);
        if (q == 0){
          u16x4 v = { f2bf(acc[m][n][0] * 0.18033688011112042f),
                      f2bf(acc[m][n][1] * 0.18033688011112042f),
                      f2bf(acc[m][n][2] * 0.18033688011112042f),
                      f2bf(acc[m][n][3] * 0.18033688011112042f) };
          *(u16x4*)(Qd + (bh*2048 + s0)*64 + kd0) = v;
        } else {
          u16x4 v = { f2bf(acc[m][n][0]), f2bf(acc[m][n][1]),
                      f2bf(acc[m][n][2]), f2bf(acc[m][n][3]) };
          *(u16x4*)(Kd + (bh*2048 + s0)*64 + kd0) = v;
        }
      }
    }
  } else {
    gemm_core<false>(xb, wb, 1024, bm, bn, ldsA, ldsB, acc);
    // reg-walk = M (s); fr = N (kd) -> transposed Vt store, s contiguous
    #pragma unroll
    for (int m = 0; m < 4; m++){
      const int i0 = bm + wm + m*16 + r4;
      const int b  = i0 >> 11;
      const int s0 = i0 & 2047;
      #pragma unroll
      for (int n = 0; n < 4; n++){
        const int ng = bn + wn + n*16 + fr;
        const int h  = (ng >> 6) & 15, kd = ng & 63;
        const size_t bh = (size_t)(b * 16 + h);
        u16x4 v = { f2bf(acc[m][n][0]), f2bf(acc[m][n][1]),
                    f2bf(acc[m][n][2]), f2bf(acc[m][n][3]) };
        *(u16x4*)(Vtd + (bh*64 + kd)*2048 + s0) = v;
      }
    }
  }
}

// -------- out projection (SWAPOP float4 stores; T1 XCD-swizzled grid) -------
__global__ __launch_bounds__(256, 3) void gemm_outp(const u16* __restrict__ attnb,
                                                    const u16* __restrict__ wob,
                                                    float* __restrict__ C)
{
  __shared__ __align__(16) u16 ldsA[128*64];
  __shared__ __align__(16) u16 ldsB[128*64];
  f32x4 acc[4][4];
  const int wg  = blockIdx.x;
  const int xcd = wg & 7, rr = wg >> 3;          // rr in [0,64)
  const int bm  = (xcd * 8 + (rr & 7)) * 128;    // 64 bm-tiles
  const int bn  = (rr >> 3) * 128;               // 8 bn-tiles
  gemm_core<true>(attnb, wob, 1024, bm, bn, ldsA, ldsB, acc);

  const int lane = threadIdx.x & 63, wave = threadIdx.x >> 6;
  const int wm = (wave >> 1) * 64, wn = (wave & 1) * 64;
  const int fr = lane & 15, r4 = (lane >> 4) * 4;
  #pragma unroll
  for (int m = 0; m < 4; m++){
    const int i0 = bm + wm + m*16 + fr;          // fr = M row
    #pragma unroll
    for (int n = 0; n < 4; n++){
      const int ng0 = bn + wn + n*16 + r4;       // 4 consecutive cols
      *(f32x4*)(C + (size_t)i0 * 1024 + ng0) = acc[m][n];
    }
  }
}

// ---- exp2+pack of one score fragment set (shift-free) ----
DEV void softmax_pack(f32x4 (&sc)[4], s16x4 (&pb)[4], int kb, int q0,
                      int fr, int r4)
{
  if (kb + 63 > q0){                 // diagonal tile: causal mask
    const int q_g = q0 + fr;
    #pragma unroll
    for (int mi = 0; mi < 4; mi++)
      #pragma unroll
      for (int r = 0; r < 4; r++){
        const int s_g = kb + mi*16 + r4 + r;
        sc[mi][r] = (s_g > q_g) ? -1e30f : sc[mi][r];   // exp2 -> 0
      }
  }
  #pragma unroll
  for (int mi = 0; mi < 4; mi++){
    f32x4 e;
    #pragma unroll
    for (int r = 0; r < 4; r++)
      e[r] = exp2_fast(sc[mi][r]);
    pb[mi] = __builtin_bit_cast(s16x4, __builtin_convertvector(e, bf16x4));
  }
}

// ---- one 64-key tile for ONE 16-row q group ----
DEV void chunk_step1(const u16* Kc, const u16* Vc, int kb, int q0,
                     const s16x8 (&qf)[2], f32x4 (&O)[4], f32x4 &L,
                     s16x4 ones, int fr, int g, int f, int r4)
{
  f32x4 sc[4];
  #pragma unroll
  for (int mi = 0; mi < 4; mi++){ f32x4 z = {0.f,0.f,0.f,0.f}; sc[mi] = z; }
  __builtin_amdgcn_s_setprio(1);
  #pragma unroll
  for (int kk = 0; kk < 2; kk++)
    #pragma unroll
    for (int mi = 0; mi < 4; mi++){
      s16x8 kf = *(const s16x8*)(Kc + (mi*16 + fr)*64 + ((kk*4 + g) ^ f)*8);
      sc[mi] = mfma16(kf, qf[kk], sc[mi]);
    }
  __builtin_amdgcn_s_setprio(0);

  s16x4 pb[4];
  softmax_pack(sc, pb, kb, q0, fr, r4);

  __builtin_amdgcn_s_setprio(1);
  #pragma unroll
  for (int mi = 0; mi < 4; mi++){
    L = mfma16k(ones, pb[mi], L);
    #pragma unroll
    for (int n = 0; n < 4; n++){
      s16x4 vf = *(const s16x4*)(Vc + (n*16 + fr)*64 + ((2*mi + (g >> 1)) ^ f)*8 + (g & 1)*4);
      O[n] = mfma16k(vf, pb[mi], O[n]);
    }
  }
  __builtin_amdgcn_s_setprio(0);
}

// ------- causal flash attention (v7: half-pair blocks, shift-free SM) -------
__global__ __launch_bounds__(256, 4) void attn_fwd(const u16* __restrict__ Qd,
                                                   const u16* __restrict__ Kd,
                                                   const u16* __restrict__ Vtd,
                                                   u16* __restrict__ attnb)
{
  __shared__ __align__(16) u16 Kl[2][64*64];
  __shared__ __align__(16) u16 Vl[2][64*64];

  const int t = threadIdx.x;
  const int lane = t & 63, w = t >> 6;
  const int wg = blockIdx.x;
  const int bh = 8 * (wg & 7) + (wg >> 7);   // same bh -> same XCD
  const int ph = (wg >> 3) & 15;
  const int p  = ph >> 1, half = ph & 1;
  const int qh = 8 + p, ql = 7 - p;          // complementary pair
  const u16* Qp = Qd  + (size_t)bh * 2048 * 64;
  const u16* Kp = Kd  + (size_t)bh * 2048 * 64;
  const u16* Vp = Vtd + (size_t)bh * 64 * 2048;

  const int fr = lane & 15, g = lane >> 4;
  const int f  = fr & 7;
  const int k8 = g * 8, r4 = g * 4;
  const int rgs = half * 4 + w;              // rg slot 0..7 within each chunk
  const int qh0 = qh * 128 + rgs * 16;
  const int ql0 = ql * 128 + rgs * 16;
  const int nkt = 2 * qh + 2;

  const s16x4 ones = { 0x3F80, 0x3F80, 0x3F80, 0x3F80 };   // bf16 1.0

  s16x8 qfh[2], qfl[2];
  #pragma unroll
  for (int kk = 0; kk < 2; kk++){
    qfh[kk] = *(const s16x8*)(Qp + (size_t)(qh0 + fr) * 64 + kk*32 + k8);
    qfl[kk] = *(const s16x8*)(Qp + (size_t)(ql0 + fr) * 64 + kk*32 + k8);
  }

  f32x4 Ohi[4], Olo[4], Lhi, Llo;
  #pragma unroll
  for (int n = 0; n < 4; n++){
    f32x4 z = {0.f,0.f,0.f,0.f}; Ohi[n] = z; Olo[n] = z;
  }
  { f32x4 z = {0.f,0.f,0.f,0.f}; Lhi = z; Llo = z; }

  // staging pointers (swizzled source, linear LDS dest), incremented per tile
  const int Lr  = t >> 3;
  const int cs8 = ((t & 7) ^ (Lr & 7)) * 8;
  const u16* kS = Kp + Lr * 64 + cs8;
  const u16* vS = Vp + (size_t)Lr * 2048 + cs8;

  // stage tile 0 into buffer 0
  gl_lds16(kS,         (u16*)Kl + t*8);
  gl_lds16(kS + 2048,  (u16*)Kl + t*8 + 2048);
  gl_lds16(vS,         (u16*)Vl + t*8);
  gl_lds16(vS + 65536, (u16*)Vl + t*8 + 2048);
  kS += 4096; vS += 64;

  for (int kt = 0; kt < nkt; ++kt){
    __syncthreads();
    const int cur = kt & 1;
    if (kt + 1 < nkt){
      u16* kD = (u16*)Kl + (cur ^ 1) * 4096 + t*8;
      u16* vD = (u16*)Vl + (cur ^ 1) * 4096 + t*8;
      gl_lds16(kS,         kD);
      gl_lds16(kS + 2048,  kD + 2048);
      gl_lds16(vS,         vD);
      gl_lds16(vS + 65536, vD + 2048);
    }
    kS += 4096; vS += 64;

    const int kb = kt * 64;
    const u16* Kc = Kl[cur];
    const u16* Vc = Vl[cur];

    if (kb <= qh0 + 15)
      chunk_step1(Kc, Vc, kb, qh0, qfh, Ohi, Lhi, ones, fr, g, f, r4);
    if (kb <= ql0 + 15)
      chunk_step1(Kc, Vc, kb, ql0, qfl, Olo, Llo, ones, fr, g, f, r4);
  }

  // ---- epilogue: L[0] is the fully-reduced softmax denominator ----
  const int b = bh >> 4, h = bh & 15;
  const float invh = 1.0f / Lhi[0];
  const float invl = 1.0f / Llo[0];
  const int sh = qh0 + fr;
  const int sl = ql0 + fr;
  #pragma unroll
  for (int n = 0; n < 4; n++){
    u16x4 vh = { f2bf(Ohi[n][0]*invh), f2bf(Ohi[n][1]*invh),
                 f2bf(Ohi[n][2]*invh), f2bf(Ohi[n][3]*invh) };
    *(u16x4*)(attnb + (((size_t)b*2048 + sh)*16 + h)*64 + n*16 + r4) = vh;
    u16x4 vl = { f2bf(Olo[n][0]*invl), f2bf(Olo[n][1]*invl),
                 f2bf(Olo[n][2]*invl), f2bf(Olo[n][3]*invl) };
    *(u16x4*)(attnb + (((size_t)b*2048 + sl)*16 + h)*64 + n*16 + r4) = vl;
  }
}

// ---------------- host launch ----------------
extern "C" void kernel_launch(void* const* d_in, const int* in_sizes, int n_in,
                              void* d_out, int out_size, void* d_ws, size_t ws_size,
                              hipStream_t stream)
{
  const float* x    = (const float*)d_in[0];   // (4,2048,1024)
  const float* wqkv = (const float*)d_in[1];   // (3,16,64,1024)
  const float* wo   = (const float*)d_in[2];   // (1024,1024)
  float* out = (float*)d_out;

  char* ws = (char*)d_ws;
  u16* xb    = (u16*)(ws);                     // xb/wqb/wob contiguous (cvt_all)
  u16* wqb   = (u16*)(ws + 16777216);
  u16* wob   = (u16*)(ws + 23068672);
  u16* Qd    = (u16*)(ws + 25165824);
  u16* Kd    = (u16*)(ws + 41943040);
  u16* Vtd   = (u16*)(ws + 58720256);
  u16* attnb = xb;                             // x dead after gemm_qkv

  cvt_all<<<3072, 256, 0, stream>>>(x, wqkv, wo, xb);
  gemm_qkv<<<dim3(1536), 256, 0, stream>>>(xb, wqb, Qd, Kd, Vtd);
  attn_fwd<<<dim3(1024), 256, 0, stream>>>(Qd, Kd, Vtd, attnb);
  gemm_outp<<<dim3(512), 256, 0, stream>>>(attnb, wob, out);
}